// Round 5
// baseline (198.165 us; speedup 1.0000x reference)
//
#include <hip/hip_runtime.h>
#include <math.h>

// NetVLAD: B=16, H=W=56 (HW=3136), D=512, K=32, fp32 in/out.
// Round 12: repair R11's NaN. Static dataflow of R11 re-derived and proven
// correct (layouts/swizzle/coverage/bounds all check); failure must be one of
// the two DYNAMIC novelties: (1) v_cvt_pk_bf16_f32 inline asm feeding MFMA
// operands, (2) phase-2 LDS write->read with no waitcnt-bearing barrier
// (relied on per-wave in-order DS + compiler alias ordering). Both are
// neutralized: f2bf (R7-R10-proven) everywhere, and one __syncthreads after
// each phase-2 stage (4 total; its s_waitcnt lgkmcnt(0) is the drain).
// Kept from R11: phase-1 A-frags DIRECT global->reg (no xs staging, no
// barriers in the s-GEMM loop), wt staged once (barrier #1), softmax->aT in
// LDS (barrier #2), xt overlays wt, wave-private phase-2 rows. 6 barriers
// total vs R10's 17.

#define BATCH 16
#define HW    3136
#define DIM   512
#define KCL   32
#define NCHK  49                     // 64-pos chunks per batch (49*64 = 3136)
#define SLABF (BATCH * DIM * KCL + 256)   // padded slab stride in floats

typedef __attribute__((ext_vector_type(8))) short short8;
typedef __attribute__((ext_vector_type(4))) float f32x4;

__device__ __forceinline__ void atomAddF(float* p, float v) {
    unsafeAtomicAdd(p, v);
}

__device__ __forceinline__ unsigned short f2bf(float f) {  // RNE fp32->bf16
    unsigned u = __float_as_uint(f);
    return (unsigned short)((u + 0x7FFFu + ((u >> 16) & 1u)) >> 16);
}

__device__ __forceinline__ short8 pack_frag(float4 lo, float4 hi) {
    union { unsigned short h[8]; short8 s; } r;
    r.h[0] = f2bf(lo.x); r.h[1] = f2bf(lo.y); r.h[2] = f2bf(lo.z); r.h[3] = f2bf(lo.w);
    r.h[4] = f2bf(hi.x); r.h[5] = f2bf(hi.y); r.h[6] = f2bf(hi.z); r.h[7] = f2bf(hi.w);
    return r.s;
}

// ---------------- K1: s = x.Wc (MFMA) + softmax (in LDS) + v = xT.a --------
// grid 784 (16 b x 49 chunks), block 256 = 4 waves, LDS 38400B.
// Phase-1 frags: A[m=l15 (pos)][k=quad*8+j (d)] direct from global;
// B[k=quad*8+j][n=l15] from wt (WcT[32k][512d] bf16, staged once);
// D[row=quad*4+reg][col=l15] (m89/m120 layouts). 16 chunks of 32 d, 2-deep
// reg prefetch, no barriers in the loop. Softmax -> aT[k][pos] bf16.
// Phase-2: wave wv owns d rows [wv*32, wv*32+32) per 128-d chunk; stages its
// own rows (transposed, XOR-swizzled pos granule 8) into its PRIVATE xt slice
// (overlaying wt; dead after barrier #2); one __syncthreads per chunk drains
// the stage writes. MFMA D[m=d][n=k] += A[d][pos].B[pos][k]; store slab.
#define WT_STR 520   // shorts per k row of WcT (512 d + 8 pad)
#define AT_STR 72    // shorts per k row of aT  (64 pos + 8 pad)
#define XT_STR 72    // shorts per d row of xt  (64 pos + 8 pad)

#define LOAD_PF(PF, DC)                                                        \
    _Pragma("unroll")                                                          \
    for (int i = 0; i < 8; ++i) {                                              \
        const int p = (ph + 2 * i) * 4;                                        \
        _Pragma("unroll")                                                      \
        for (int j = 0; j < 4; ++j)                                            \
            PF[i * 4 + j] = xc[(size_t)(p + j) * DIM + (DC)];                  \
    }

#define P2_STAGE(PF)                                                           \
    _Pragma("unroll")                                                          \
    for (int i = 0; i < 8; ++i) {                                              \
        const int p = (ph + 2 * i) * 4;                                        \
        ushort4 w;                                                             \
        w.x = f2bf(PF[i * 4 + 0]); w.y = f2bf(PF[i * 4 + 1]);                  \
        w.z = f2bf(PF[i * 4 + 2]); w.w = f2bf(PF[i * 4 + 3]);                  \
        *(ushort4*)&xt[xtrow * XT_STR + (p ^ xsw)] = w;                        \
    }

#define P2_MFMA_STORE(DC)                                                      \
    {                                                                          \
        f32x4 z = {0.f, 0.f, 0.f, 0.f};                                        \
        f32x4 pacc[2][2];                                                      \
        pacc[0][0] = z; pacc[0][1] = z; pacc[1][0] = z; pacc[1][1] = z;        \
        _Pragma("unroll")                                                      \
        for (int s_ = 0; s_ < 2; ++s_) {                                       \
            const int pb = s_ * 32 + quad * 8;                                 \
            short8 bf0 = *(const short8*)&aT[l15 * AT_STR + pb];               \
            short8 bf1 = *(const short8*)&aT[(16 + l15) * AT_STR + pb];        \
            _Pragma("unroll")                                                  \
            for (int m2 = 0; m2 < 2; ++m2) {                                   \
                const int dloc = wv * 32 + m2 * 16 + l15;                      \
                short8 af = *(const short8*)&xt[dloc * XT_STR + (pb ^ (((dloc >> 3) & 7) << 3))]; \
                pacc[m2][0] = __builtin_amdgcn_mfma_f32_16x16x32_bf16(af, bf0, pacc[m2][0], 0, 0, 0); \
                pacc[m2][1] = __builtin_amdgcn_mfma_f32_16x16x32_bf16(af, bf1, pacc[m2][1], 0, 0, 0); \
            }                                                                  \
        }                                                                      \
        _Pragma("unroll")                                                      \
        for (int m2 = 0; m2 < 2; ++m2) {                                       \
            const int dr = (DC) + (wv * 2 + m2) * 16 + quad * 4;               \
            _Pragma("unroll")                                                  \
            for (int r = 0; r < 4; ++r) {                                      \
                vp[(size_t)(dr + r) * KCL + l15]      = pacc[m2][0][r];        \
                vp[(size_t)(dr + r) * KCL + 16 + l15] = pacc[m2][1][r];        \
            }                                                                  \
        }                                                                      \
    }

__global__ __launch_bounds__(256, 3) void k_sax(const float* __restrict__ x,
                                                const float* __restrict__ Wc,
                                                float* __restrict__ vpart,
                                                float* __restrict__ a_sum) {
    __shared__ __align__(16) unsigned short wt[32 * WT_STR];  // 33280 B (phase-2: xt[128][72] overlay)
    __shared__ __align__(16) unsigned short aT[KCL * AT_STR]; //  4608 B
    __shared__ float asum_l[4][32];                           //   512 B
    const int t    = threadIdx.x;
    const int lane = t & 63;
    const int wv   = t >> 6;
    const int l15  = lane & 15;
    const int quad = lane >> 4;
    const int n0   = blockIdx.x * 64;
    const int b    = n0 / HW;          // uniform per block (64 | 3136)
    const int ch   = blockIdx.x % NCHK;

    // ---- phase-1 A-frag base: this wave's pos row l15, d offset quad*8
    const float* xr = x + (size_t)(n0 + wv * 16 + l15) * DIM + quad * 8;

    // issue chunk 0,1 A-loads first (deepest in the VMEM queue)
    float4 afb[2][2];
#pragma unroll
    for (int c = 0; c < 2; ++c) {
        afb[c][0] = *(const float4*)(xr + c * 32);
        afb[c][1] = *(const float4*)(xr + c * 32 + 4);
    }

    // ---- stage WcT[32 k][512 d] bf16, once
#pragma unroll
    for (int i = 0; i < 16; ++i) {
        int f  = i * 256 + t;          // 0..4095 float4s of Wc
        int d  = f >> 3;               // 0..511
        int k4 = (f & 7) * 4;
        float4 v = *(const float4*)(Wc + (size_t)d * KCL + k4);
        wt[(k4 + 0) * WT_STR + d] = f2bf(v.x);
        wt[(k4 + 1) * WT_STR + d] = f2bf(v.y);
        wt[(k4 + 2) * WT_STR + d] = f2bf(v.z);
        wt[(k4 + 3) * WT_STR + d] = f2bf(v.w);
    }
    __syncthreads();                   // barrier #1: wt visible

    // ---- phase-1: 16 chunks of 32 d, barrier-free, 2-deep reg prefetch
    f32x4 acc0 = {0.f, 0.f, 0.f, 0.f};
    f32x4 acc1 = {0.f, 0.f, 0.f, 0.f};
#pragma unroll
    for (int c = 0; c < 16; ++c) {
        float4 lo = afb[c & 1][0], hi = afb[c & 1][1];
        if (c < 14) {
            afb[c & 1][0] = *(const float4*)(xr + (c + 2) * 32);
            afb[c & 1][1] = *(const float4*)(xr + (c + 2) * 32 + 4);
        }
        short8 af = pack_frag(lo, hi);
        short8 b0 = *(const short8*)&wt[l15 * WT_STR + c * 32 + quad * 8];
        short8 b1 = *(const short8*)&wt[(16 + l15) * WT_STR + c * 32 + quad * 8];
        acc0 = __builtin_amdgcn_mfma_f32_16x16x32_bf16(af, b0, acc0, 0, 0, 0);
        acc1 = __builtin_amdgcn_mfma_f32_16x16x32_bf16(af, b1, acc1, 0, 0, 0);
    }

    // ---- softmax over 32 k per position (row = quad*4+reg, col k = l15/+16)
    float at0 = 0.f, at1 = 0.f;
#pragma unroll
    for (int r = 0; r < 4; ++r) {
        float m = fmaxf(acc0[r], acc1[r]);
        m = fmaxf(m, __shfl_xor(m, 1));
        m = fmaxf(m, __shfl_xor(m, 2));
        m = fmaxf(m, __shfl_xor(m, 4));
        m = fmaxf(m, __shfl_xor(m, 8));
        float e0 = __expf(acc0[r] - m);
        float e1 = __expf(acc1[r] - m);
        float s = e0 + e1;
        s += __shfl_xor(s, 1);
        s += __shfl_xor(s, 2);
        s += __shfl_xor(s, 4);
        s += __shfl_xor(s, 8);
        float inv = 1.f / s;
        float a0 = e0 * inv, a1 = e1 * inv;
        const int pos = wv * 16 + quad * 4 + r;        // local 0..63
        aT[l15 * AT_STR + pos]        = f2bf(a0);
        aT[(16 + l15) * AT_STR + pos] = f2bf(a1);
        at0 += a0; at1 += a1;
    }
    at0 += __shfl_xor(at0, 16); at0 += __shfl_xor(at0, 32);
    at1 += __shfl_xor(at1, 16); at1 += __shfl_xor(at1, 32);
    if (quad == 0) {
        asum_l[wv][l15]      = at0;
        asum_l[wv][16 + l15] = at1;
    }

    // ---- phase-2 setup: wave-private 32 d-rows per 128-d chunk
    const int rw    = lane & 31;       // row within this wave's slice
    const int ph    = lane >> 5;       // pos half (0/1)
    const int xtrow = wv * 32 + rw;    // row in xt[128][XT_STR]
    const int xsw   = ((xtrow >> 3) & 7) << 3;
    unsigned short* xt = wt;           // overlay (wt dead after barrier #2)
    const float* xc = x + (size_t)n0 * DIM + xtrow;   // + (p+j)*DIM + dc
    float* vp = vpart + (size_t)ch * SLABF + (size_t)b * DIM * KCL;

    float pfA[32], pfB[32];
    LOAD_PF(pfA, 0);                   // issue before the barrier

    __syncthreads();                   // barrier #2: aT/asum ready, wt dead
    if (t < 32)
        atomAddF(&a_sum[b * KCL + t],
                 asum_l[0][t] + asum_l[1][t] + asum_l[2][t] + asum_l[3][t]);

    LOAD_PF(pfB, 128);

    // ---- phase-2: 4 chunks; one barrier per chunk drains stage writes
    P2_STAGE(pfA);
    __syncthreads();                   // drain chunk-0 writes
    LOAD_PF(pfA, 256);
    P2_MFMA_STORE(0);
    P2_STAGE(pfB);
    __syncthreads();                   // drain chunk-1 writes
    LOAD_PF(pfB, 384);
    P2_MFMA_STORE(128);
    P2_STAGE(pfA);
    __syncthreads();                   // drain chunk-2 writes
    P2_MFMA_STORE(256);
    P2_STAGE(pfB);
    __syncthreads();                   // drain chunk-3 writes
    P2_MFMA_STORE(384);
}

// ---------------- K3: reduce chunk slabs + C*a_sum + intra-normalize -------
// grid 1024, block 256: 8 rows x 32 k; compile-time 49-slab loop, unroll x4.
__global__ __launch_bounds__(256) void k_norm1(const float* __restrict__ vpart,
                                               const float* __restrict__ a_sum,
                                               const float* __restrict__ Cc,
                                               float* __restrict__ out,
                                               float* __restrict__ ssq) {
    const int t = threadIdx.x;
    const int row = blockIdx.x * 8 + (t >> 5);
    const int k = t & 31;
    const int b = row >> 9;            // uniform per block (8 | 512)
    const int d = row & 511;

    const float* vp = vpart + (size_t)row * KCL + k;
    float s0 = 0.f, s1 = 0.f, s2 = 0.f, s3 = 0.f;
#pragma unroll
    for (int ps = 0; ps < 48; ps += 4) {
        s0 += vp[(size_t)(ps + 0) * SLABF];
        s1 += vp[(size_t)(ps + 1) * SLABF];
        s2 += vp[(size_t)(ps + 2) * SLABF];
        s3 += vp[(size_t)(ps + 3) * SLABF];
    }
    s0 += vp[(size_t)48 * SLABF];
    float v = (s0 + s1) + (s2 + s3) + Cc[d * KCL + k] * a_sum[b * KCL + k];

    float ss = v * v;
    ss += __shfl_xor(ss, 1, 32);  ss += __shfl_xor(ss, 2, 32);
    ss += __shfl_xor(ss, 4, 32);  ss += __shfl_xor(ss, 8, 32);
    ss += __shfl_xor(ss, 16, 32);
    float inv = 1.f / fmaxf(sqrtf(ss), 1e-12f);
    float r = v * inv;
    out[(size_t)row * KCL + k] = r;

    float bs = r * r;
    for (int off = 32; off > 0; off >>= 1) bs += __shfl_down(bs, off, 64);
    __shared__ float red[4];
    if ((t & 63) == 0) red[t >> 6] = bs;
    __syncthreads();
    if (t == 0) atomAddF(&ssq[b], (red[0] + red[1]) + (red[2] + red[3]));
}

// ---------------- K4: final global L2 normalize ----------------
__global__ __launch_bounds__(256) void k_norm2(float* __restrict__ out,
                                               const float* __restrict__ ssq) {
    const int i4 = blockIdx.x * 256 + threadIdx.x;
    const int b = i4 >> 12;
    float inv = 1.f / fmaxf(sqrtf(ssq[b]), 1e-12f);
    float4 v = *(float4*)(out + (size_t)i4 * 4);
    v.x *= inv; v.y *= inv; v.z *= inv; v.w *= inv;
    *(float4*)(out + (size_t)i4 * 4) = v;
}

extern "C" void kernel_launch(void* const* d_in, const int* in_sizes, int n_in,
                              void* d_out, int out_size, void* d_ws, size_t ws_size,
                              hipStream_t stream) {
    const float* x  = (const float*)d_in[0];
    const float* Wc = (const float*)d_in[1];
    const float* Cc = (const float*)d_in[2];
    float* out = (float*)d_out;

    // ws: vpart 49 padded slabs (51.5 MB) | a_sum (2 KB) | ssq (64 B)
    char* ws = (char*)d_ws;
    float* vpart = (float*)ws;
    float* a_sum = (float*)(ws + (size_t)NCHK * SLABF * 4);
    float* ssq   = (float*)(ws + (size_t)NCHK * SLABF * 4 + 2048);

    hipMemsetAsync(a_sum, 0, 2048 + 64, stream);

    k_sax  <<<784, 256, 0, stream>>>(x, Wc, vpart, a_sum);
    k_norm1<<<1024, 256, 0, stream>>>(vpart, a_sum, Cc, out, ssq);
    k_norm2<<<256, 256, 0, stream>>>(out, ssq);
}

// Round 6
// 196.214 us; speedup vs baseline: 1.0099x; 1.0099x over previous
//
#include <hip/hip_runtime.h>
#include <math.h>

// NetVLAD: B=16, H=W=56 (HW=3136), D=512, K=32, fp32 in/out.
// Round 13: take load issue/wait control from the compiler. R8-R12: k_sax
// pinned at 65-68us over five variants; VGPR=68 proves reg-prefetch was sunk
// to use sites every time (pipeline deleted) -> ~900cy exposed HBM latency
// per step, all pipes <30%. Fix = T14/m218 pattern in plain HIP:
//  - every x load is asm volatile global_load (pinned at issue site),
//    consumed after counted s_waitcnt vmcnt(N) + sched_barrier(0) (rule #18).
//  - phase-1: 8-deep afb pipeline; prologue issues 8 pairs before wt staging;
//    explicit vmcnt(0) after barrier #1 (compiler can't track asm loads);
//    tail iters wait vmcnt(2*(15-c)).
//  - phase-2: ZERO barriers (xt slices wave-private, aT read-only after
//    barrier #2, vpart stores disjoint); waves free-run across chunks.
//    vmcnt ledger per wave (issue order pfA|pfB,st0,pfA',st128,pfB',st256):
//    waits 0 / 48 / 48 / 16 release exactly the needed pf buffer.
//  - a_sum atomic moved to kernel end (out of the counted region).
// Barriers: 2 total. Math identical to R12 (absmax 1.22e-4 expected).

#define BATCH 16
#define HW    3136
#define DIM   512
#define KCL   32
#define NCHK  49                     // 64-pos chunks per batch (49*64 = 3136)
#define SLABF (BATCH * DIM * KCL + 256)   // padded slab stride in floats

typedef __attribute__((ext_vector_type(8))) short short8;
typedef __attribute__((ext_vector_type(4))) float f32x4;

__device__ __forceinline__ void atomAddF(float* p, float v) {
    unsafeAtomicAdd(p, v);
}

__device__ __forceinline__ unsigned short f2bf(float f) {  // RNE fp32->bf16
    unsigned u = __float_as_uint(f);
    return (unsigned short)((u + 0x7FFFu + ((u >> 16) & 1u)) >> 16);
}

__device__ __forceinline__ short8 pack_frag(f32x4 lo, f32x4 hi) {
    union { unsigned short h[8]; short8 s; } r;
    r.h[0] = f2bf(lo[0]); r.h[1] = f2bf(lo[1]); r.h[2] = f2bf(lo[2]); r.h[3] = f2bf(lo[3]);
    r.h[4] = f2bf(hi[0]); r.h[5] = f2bf(hi[1]); r.h[6] = f2bf(hi[2]); r.h[7] = f2bf(hi[3]);
    return r.s;
}

// Pinned-issue loads: volatile asm cannot be sunk by the scheduler.
// The result register is NOT valid until an explicit s_waitcnt vmcnt.
__device__ __forceinline__ f32x4 gload4(const float* p) {
    f32x4 r;
    asm volatile("global_load_dwordx4 %0, %1, off" : "=v"(r) : "v"(p) : "memory");
    return r;
}
__device__ __forceinline__ float gload1(const float* p) {
    float r;
    asm volatile("global_load_dword %0, %1, off" : "=v"(r) : "v"(p) : "memory");
    return r;
}

#define WAITV(N)                                                               \
    do {                                                                       \
        asm volatile("s_waitcnt vmcnt(" #N ")" ::: "memory");                  \
        __builtin_amdgcn_sched_barrier(0);                                     \
    } while (0)

// ---------------- K1: s = x.Wc (MFMA) + softmax (in LDS) + v = xT.a --------
// grid 784 (16 b x 49 chunks), block 256 = 4 waves, LDS 38400B.
// Phase-1 frags: A[m=l15 (pos)][k=quad*8+j (d)] direct global->reg (asm,
// 8-deep); B[k=quad*8+j][n=l15] from wt (WcT[32k][512d] bf16, staged once);
// D[row=quad*4+reg][col=l15] (m89/m120 layouts). Softmax -> aT[k][pos] bf16.
// Phase-2: wave wv owns xt rows [wv*32,+32) per 128-d chunk (PRIVATE ->
// barrier-free); x re-read (L2/L3-hot) via pinned scalar loads, 2-buf,
// counted vmcnt; MFMA D[m=d][n=k] += A[d][pos].B[pos][k]; store slab.
#define WT_STR 520   // shorts per k row of WcT (512 d + 8 pad)
#define AT_STR 72    // shorts per k row of aT  (64 pos + 8 pad)
#define XT_STR 72    // shorts per d row of xt  (64 pos + 8 pad)

#define P1_TAIL(C, N)                                                          \
    {                                                                          \
        asm volatile("s_waitcnt vmcnt(" #N ")" ::: "memory");                  \
        __builtin_amdgcn_sched_barrier(0);                                     \
        short8 af = pack_frag(afb[(C) & 7][0], afb[(C) & 7][1]);               \
        short8 b0 = *(const short8*)&wt[l15 * WT_STR + (C) * 32 + quad * 8];   \
        short8 b1 = *(const short8*)&wt[(16 + l15) * WT_STR + (C) * 32 + quad * 8]; \
        acc0 = __builtin_amdgcn_mfma_f32_16x16x32_bf16(af, b0, acc0, 0, 0, 0); \
        acc1 = __builtin_amdgcn_mfma_f32_16x16x32_bf16(af, b1, acc1, 0, 0, 0); \
    }

#define LOAD_PF_ASM(PF, DC)                                                    \
    _Pragma("unroll")                                                          \
    for (int i = 0; i < 8; ++i) {                                              \
        const int p = (ph + 2 * i) * 4;                                        \
        _Pragma("unroll")                                                      \
        for (int j = 0; j < 4; ++j)                                            \
            PF[i * 4 + j] = gload1(xc + (size_t)(p + j) * DIM + (DC));         \
    }

#define P2_STAGE(PF)                                                           \
    _Pragma("unroll")                                                          \
    for (int i = 0; i < 8; ++i) {                                              \
        const int p = (ph + 2 * i) * 4;                                        \
        ushort4 w;                                                             \
        w.x = f2bf(PF[i * 4 + 0]); w.y = f2bf(PF[i * 4 + 1]);                  \
        w.z = f2bf(PF[i * 4 + 2]); w.w = f2bf(PF[i * 4 + 3]);                  \
        *(ushort4*)&xt[xtrow * XT_STR + (p ^ xsw)] = w;                        \
    }

#define P2_MFMA_STORE(DC)                                                      \
    {                                                                          \
        f32x4 z = {0.f, 0.f, 0.f, 0.f};                                        \
        f32x4 pacc[2][2];                                                      \
        pacc[0][0] = z; pacc[0][1] = z; pacc[1][0] = z; pacc[1][1] = z;        \
        _Pragma("unroll")                                                      \
        for (int s_ = 0; s_ < 2; ++s_) {                                       \
            const int pb = s_ * 32 + quad * 8;                                 \
            short8 bf0 = *(const short8*)&aT[l15 * AT_STR + pb];               \
            short8 bf1 = *(const short8*)&aT[(16 + l15) * AT_STR + pb];        \
            _Pragma("unroll")                                                  \
            for (int m2 = 0; m2 < 2; ++m2) {                                   \
                const int dloc = wv * 32 + m2 * 16 + l15;                      \
                short8 af = *(const short8*)&xt[dloc * XT_STR + (pb ^ (((dloc >> 3) & 7) << 3))]; \
                pacc[m2][0] = __builtin_amdgcn_mfma_f32_16x16x32_bf16(af, bf0, pacc[m2][0], 0, 0, 0); \
                pacc[m2][1] = __builtin_amdgcn_mfma_f32_16x16x32_bf16(af, bf1, pacc[m2][1], 0, 0, 0); \
            }                                                                  \
        }                                                                      \
        _Pragma("unroll")                                                      \
        for (int m2 = 0; m2 < 2; ++m2) {                                       \
            const int dr = (DC) + (wv * 2 + m2) * 16 + quad * 4;               \
            _Pragma("unroll")                                                  \
            for (int r = 0; r < 4; ++r) {                                      \
                vp[(size_t)(dr + r) * KCL + l15]      = pacc[m2][0][r];        \
                vp[(size_t)(dr + r) * KCL + 16 + l15] = pacc[m2][1][r];        \
            }                                                                  \
        }                                                                      \
    }

__global__ __launch_bounds__(256, 3) void k_sax(const float* __restrict__ x,
                                                const float* __restrict__ Wc,
                                                float* __restrict__ vpart,
                                                float* __restrict__ a_sum) {
    __shared__ __align__(16) unsigned short wt[32 * WT_STR];  // 33280 B (phase-2: xt[128][72] overlay)
    __shared__ __align__(16) unsigned short aT[KCL * AT_STR]; //  4608 B
    __shared__ float asum_l[4][32];                           //   512 B
    const int t    = threadIdx.x;
    const int lane = t & 63;
    const int wv   = t >> 6;
    const int l15  = lane & 15;
    const int quad = lane >> 4;
    const int n0   = blockIdx.x * 64;
    const int b    = n0 / HW;          // uniform per block (64 | 3136)
    const int ch   = blockIdx.x % NCHK;

    // ---- phase-1 A-frag base: this wave's pos row l15, d offset quad*8
    const float* xr = x + (size_t)(n0 + wv * 16 + l15) * DIM + quad * 8;

    // prologue: pin-issue pairs for chunks 0..7 (latency hides under staging)
    f32x4 afb[8][2];
#pragma unroll
    for (int c = 0; c < 8; ++c) {
        afb[c][0] = gload4(xr + c * 32);
        afb[c][1] = gload4(xr + c * 32 + 4);
    }

    // ---- stage WcT[32 k][512 d] bf16, once (compiler loads, L2-hot)
#pragma unroll
    for (int i = 0; i < 16; ++i) {
        int f  = i * 256 + t;          // 0..4095 float4s of Wc
        int d  = f >> 3;               // 0..511
        int k4 = (f & 7) * 4;
        float4 v = *(const float4*)(Wc + (size_t)d * KCL + k4);
        wt[(k4 + 0) * WT_STR + d] = f2bf(v.x);
        wt[(k4 + 1) * WT_STR + d] = f2bf(v.y);
        wt[(k4 + 2) * WT_STR + d] = f2bf(v.z);
        wt[(k4 + 3) * WT_STR + d] = f2bf(v.w);
    }
    __syncthreads();                   // barrier #1: wt visible
    WAITV(0);                          // drain prologue (untracked by compiler)

    // ---- phase-1: 16 chunks of 32 d, no barriers; counted-vmcnt pipeline
    f32x4 acc0 = {0.f, 0.f, 0.f, 0.f};
    f32x4 acc1 = {0.f, 0.f, 0.f, 0.f};
#pragma unroll
    for (int c = 0; c < 8; ++c) {
        short8 af = pack_frag(afb[c][0], afb[c][1]);
        afb[c][0] = gload4(xr + (c + 8) * 32);      // pin-issue chunk c+8
        afb[c][1] = gload4(xr + (c + 8) * 32 + 4);
        short8 b0 = *(const short8*)&wt[l15 * WT_STR + c * 32 + quad * 8];
        short8 b1 = *(const short8*)&wt[(16 + l15) * WT_STR + c * 32 + quad * 8];
        acc0 = __builtin_amdgcn_mfma_f32_16x16x32_bf16(af, b0, acc0, 0, 0, 0);
        acc1 = __builtin_amdgcn_mfma_f32_16x16x32_bf16(af, b1, acc1, 0, 0, 0);
    }
    P1_TAIL(8, 14)  P1_TAIL(9, 12)  P1_TAIL(10, 10) P1_TAIL(11, 8)
    P1_TAIL(12, 6)  P1_TAIL(13, 4)  P1_TAIL(14, 2)  P1_TAIL(15, 0)

    // ---- softmax over 32 k per position (row = quad*4+reg, col k = l15/+16)
    float at0 = 0.f, at1 = 0.f;
#pragma unroll
    for (int r = 0; r < 4; ++r) {
        float m = fmaxf(acc0[r], acc1[r]);
        m = fmaxf(m, __shfl_xor(m, 1));
        m = fmaxf(m, __shfl_xor(m, 2));
        m = fmaxf(m, __shfl_xor(m, 4));
        m = fmaxf(m, __shfl_xor(m, 8));
        float e0 = __expf(acc0[r] - m);
        float e1 = __expf(acc1[r] - m);
        float s = e0 + e1;
        s += __shfl_xor(s, 1);
        s += __shfl_xor(s, 2);
        s += __shfl_xor(s, 4);
        s += __shfl_xor(s, 8);
        float inv = 1.f / s;
        float a0 = e0 * inv, a1 = e1 * inv;
        const int pos = wv * 16 + quad * 4 + r;        // local 0..63
        aT[l15 * AT_STR + pos]        = f2bf(a0);
        aT[(16 + l15) * AT_STR + pos] = f2bf(a1);
        at0 += a0; at1 += a1;
    }
    at0 += __shfl_xor(at0, 16); at0 += __shfl_xor(at0, 32);
    at1 += __shfl_xor(at1, 16); at1 += __shfl_xor(at1, 32);
    if (quad == 0) {
        asum_l[wv][l15]      = at0;
        asum_l[wv][16 + l15] = at1;
    }

    // ---- phase-2 setup: wave-private 32 d-rows per 128-d chunk
    const int rw    = lane & 31;       // row within this wave's slice
    const int ph    = lane >> 5;       // pos half (0/1)
    const int xtrow = wv * 32 + rw;    // row in xt[128][XT_STR]
    const int xsw   = ((xtrow >> 3) & 7) << 3;
    unsigned short* xt = wt;           // overlay (wt dead after barrier #2)
    const float* xc = x + (size_t)n0 * DIM + xtrow;   // + (p+j)*DIM + dc
    float* vp = vpart + (size_t)ch * SLABF + (size_t)b * DIM * KCL;

    float pfA[32], pfB[32];
    LOAD_PF_ASM(pfA, 0);               // pin-issue before barrier #2

    __syncthreads();                   // barrier #2: aT/asum ready, wt dead

    // ---- phase-2: barrier-free, counted-vmcnt 2-buf pipeline.
    // Per-wave issue order: pfA | pfB, st0(16), pfA' | st128(16), pfB' |
    // st256(16). Waits 0/48/48/16 release exactly the needed buffer.
    WAITV(0);                          // pfA ready (only pfA in flight)
    LOAD_PF_ASM(pfB, 128);
    P2_STAGE(pfA);
    P2_MFMA_STORE(0);                  // +16 stores
    LOAD_PF_ASM(pfA, 256);
    WAITV(48);                         // pfB done (st0 + pfA' remain)
    P2_STAGE(pfB);
    P2_MFMA_STORE(128);                // +16 stores
    LOAD_PF_ASM(pfB, 384);
    WAITV(48);                         // pfA' done (st128 + pfB' remain)
    P2_STAGE(pfA);
    P2_MFMA_STORE(256);                // +16 stores
    WAITV(16);                         // pfB' done (st256 remains)
    P2_STAGE(pfB);
    P2_MFMA_STORE(384);

    // a_sum atomic at end (outside the counted region)
    if (t < 32)
        atomAddF(&a_sum[b * KCL + t],
                 asum_l[0][t] + asum_l[1][t] + asum_l[2][t] + asum_l[3][t]);
}

// ---------------- K3: reduce chunk slabs + C*a_sum + intra-normalize -------
// grid 1024, block 256: 8 rows x 32 k; compile-time 49-slab loop, unroll x4.
__global__ __launch_bounds__(256) void k_norm1(const float* __restrict__ vpart,
                                               const float* __restrict__ a_sum,
                                               const float* __restrict__ Cc,
                                               float* __restrict__ out,
                                               float* __restrict__ ssq) {
    const int t = threadIdx.x;
    const int row = blockIdx.x * 8 + (t >> 5);
    const int k = t & 31;
    const int b = row >> 9;            // uniform per block (8 | 512)
    const int d = row & 511;

    const float* vp = vpart + (size_t)row * KCL + k;
    float s0 = 0.f, s1 = 0.f, s2 = 0.f, s3 = 0.f;
#pragma unroll
    for (int ps = 0; ps < 48; ps += 4) {
        s0 += vp[(size_t)(ps + 0) * SLABF];
        s1 += vp[(size_t)(ps + 1) * SLABF];
        s2 += vp[(size_t)(ps + 2) * SLABF];
        s3 += vp[(size_t)(ps + 3) * SLABF];
    }
    s0 += vp[(size_t)48 * SLABF];
    float v = (s0 + s1) + (s2 + s3) + Cc[d * KCL + k] * a_sum[b * KCL + k];

    float ss = v * v;
    ss += __shfl_xor(ss, 1, 32);  ss += __shfl_xor(ss, 2, 32);
    ss += __shfl_xor(ss, 4, 32);  ss += __shfl_xor(ss, 8, 32);
    ss += __shfl_xor(ss, 16, 32);
    float inv = 1.f / fmaxf(sqrtf(ss), 1e-12f);
    float r = v * inv;
    out[(size_t)row * KCL + k] = r;

    float bs = r * r;
    for (int off = 32; off > 0; off >>= 1) bs += __shfl_down(bs, off, 64);
    __shared__ float red[4];
    if ((t & 63) == 0) red[t >> 6] = bs;
    __syncthreads();
    if (t == 0) atomAddF(&ssq[b], (red[0] + red[1]) + (red[2] + red[3]));
}

// ---------------- K4: final global L2 normalize ----------------
__global__ __launch_bounds__(256) void k_norm2(float* __restrict__ out,
                                               const float* __restrict__ ssq) {
    const int i4 = blockIdx.x * 256 + threadIdx.x;
    const int b = i4 >> 12;
    float inv = 1.f / fmaxf(sqrtf(ssq[b]), 1e-12f);
    float4 v = *(float4*)(out + (size_t)i4 * 4);
    v.x *= inv; v.y *= inv; v.z *= inv; v.w *= inv;
    *(float4*)(out + (size_t)i4 * 4) = v;
}

extern "C" void kernel_launch(void* const* d_in, const int* in_sizes, int n_in,
                              void* d_out, int out_size, void* d_ws, size_t ws_size,
                              hipStream_t stream) {
    const float* x  = (const float*)d_in[0];
    const float* Wc = (const float*)d_in[1];
    const float* Cc = (const float*)d_in[2];
    float* out = (float*)d_out;

    // ws: vpart 49 padded slabs (51.5 MB) | a_sum (2 KB) | ssq (64 B)
    char* ws = (char*)d_ws;
    float* vpart = (float*)ws;
    float* a_sum = (float*)(ws + (size_t)NCHK * SLABF * 4);
    float* ssq   = (float*)(ws + (size_t)NCHK * SLABF * 4 + 2048);

    hipMemsetAsync(a_sum, 0, 2048 + 64, stream);

    k_sax  <<<784, 256, 0, stream>>>(x, Wc, vpart, a_sum);
    k_norm1<<<1024, 256, 0, stream>>>(vpart, a_sum, Cc, out, ssq);
    k_norm2<<<256, 256, 0, stream>>>(out, ssq);
}

// Round 7
// 191.579 us; speedup vs baseline: 1.0344x; 1.0242x over previous
//
#include <hip/hip_runtime.h>
#include <math.h>

// NetVLAD: B=16, H=W=56 (HW=3136), D=512, K=32, fp32 in/out.
// Round 14: keep x in registers between phases. R13 proved the 8-deep pinned
// pipeline (VGPR 80 = afb[8][2]) and counted vmcnt exist yet k_sax stays at
// 64us, 90% stall; and dur_us accounting closed: 196 = 2x392MB harness poison
// fills (~120us, fixed) + k_sax 64 + norm1 9 + norm2 1. Remaining stall is
// phase-2's 128 scalar global re-loads/thread (L3-hot but ~1000cy loaded
// latency, 2-buf depth, block-aligned waits). Fix: phase-1 already moves all
// of x through regs -> persist it as bf16 (xk[16] short8 = 64 VGPR) and stage
// the phase-2 transpose FROM REGISTERS (32 ushort LDS writes/chunk, 2-way
// bank-free with the swizzle). ALL phase-2 global loads + addr VALU + waits
// deleted. Cross-wave transpose needs 2 lgkm-only hand barriers per chunk
// (s_waitcnt lgkmcnt(0); s_barrier -- vmcnt NOT drained, vpart stores stay in
// flight). Barrier #1 also hand-rolled so the phase-1 prologue pipeline
// survives it. Compiler __syncthreads only at barrier #2 (nothing in flight).

#define BATCH 16
#define HW    3136
#define DIM   512
#define KCL   32
#define NCHK  49                     // 64-pos chunks per batch (49*64 = 3136)
#define SLABF (BATCH * DIM * KCL + 256)   // padded slab stride in floats

typedef __attribute__((ext_vector_type(8))) short short8;
typedef __attribute__((ext_vector_type(4))) float f32x4;

__device__ __forceinline__ void atomAddF(float* p, float v) {
    unsafeAtomicAdd(p, v);
}

__device__ __forceinline__ unsigned short f2bf(float f) {  // RNE fp32->bf16
    unsigned u = __float_as_uint(f);
    return (unsigned short)((u + 0x7FFFu + ((u >> 16) & 1u)) >> 16);
}

__device__ __forceinline__ short8 pack_frag(f32x4 lo, f32x4 hi) {
    union { unsigned short h[8]; short8 s; } r;
    r.h[0] = f2bf(lo[0]); r.h[1] = f2bf(lo[1]); r.h[2] = f2bf(lo[2]); r.h[3] = f2bf(lo[3]);
    r.h[4] = f2bf(hi[0]); r.h[5] = f2bf(hi[1]); r.h[6] = f2bf(hi[2]); r.h[7] = f2bf(hi[3]);
    return r.s;
}

// Pinned-issue loads: volatile asm cannot be sunk; result invalid until
// an explicit counted s_waitcnt vmcnt.
__device__ __forceinline__ f32x4 gload4(const float* p) {
    f32x4 r;
    asm volatile("global_load_dwordx4 %0, %1, off" : "=v"(r) : "v"(p) : "memory");
    return r;
}

#define WAITV(N)                                                               \
    do {                                                                       \
        asm volatile("s_waitcnt vmcnt(" #N ")" ::: "memory");                  \
        __builtin_amdgcn_sched_barrier(0);                                     \
    } while (0)

// lgkm-only barrier: LDS visibility without draining in-flight VMEM
// (prologue loads across barrier #1; vpart stores across phase-2 barriers).
#define HBAR()                                                                 \
    do {                                                                       \
        __builtin_amdgcn_sched_barrier(0);                                     \
        asm volatile("s_waitcnt lgkmcnt(0)\n\ts_barrier" ::: "memory");        \
        __builtin_amdgcn_sched_barrier(0);                                     \
    } while (0)

// ---------------- K1: s = x.Wc (MFMA) + softmax (in LDS) + v = xT.a --------
// grid 784 (16 b x 49 chunks), block 256 = 4 waves, LDS 38400B.
// Phase-1 frags: A[m=l15 (pos)][k=quad*8+j (d)] direct global->reg (asm,
// 8-deep pipeline), persisted as bf16 in xk[16]; B[k][n=l15] from wt
// (WcT[32k][512d] bf16, staged once); D[row=quad*4+reg][col=l15]
// (m89/m120 layouts). Softmax -> aT[k][pos] bf16.
// Phase-2: per 128-d chunk, xt[d][pos] (overlay on wt) staged FROM xk regs
// (cross-wave transpose, 2 lgkm hand-barriers/chunk); pos XOR-swizzled
// granule 8 by row (2-way bank-free writes + reads). MFMA D[m=d][n=k] +=
// A[d][pos].B[pos][k]; store slab.
#define WT_STR 520   // shorts per k row of WcT (512 d + 8 pad)
#define AT_STR 72    // shorts per k row of aT  (64 pos + 8 pad)
#define XT_STR 72    // shorts per d row of xt  (64 pos + 8 pad)

#define P1_ITER(C)                                                             \
    {                                                                          \
        WAITV(14);                                                             \
        xk[C] = pack_frag(afb[(C) & 7][0], afb[(C) & 7][1]);                   \
        afb[(C) & 7][0] = gload4(xr + ((C) + 8) * 32);                         \
        afb[(C) & 7][1] = gload4(xr + ((C) + 8) * 32 + 4);                     \
        short8 b0 = *(const short8*)&wt[l15 * WT_STR + (C) * 32 + quad * 8];   \
        short8 b1 = *(const short8*)&wt[(16 + l15) * WT_STR + (C) * 32 + quad * 8]; \
        acc0 = __builtin_amdgcn_mfma_f32_16x16x32_bf16(xk[C], b0, acc0, 0, 0, 0); \
        acc1 = __builtin_amdgcn_mfma_f32_16x16x32_bf16(xk[C], b1, acc1, 0, 0, 0); \
    }

#define P1_TAIL(C, N)                                                          \
    {                                                                          \
        asm volatile("s_waitcnt vmcnt(" #N ")" ::: "memory");                  \
        __builtin_amdgcn_sched_barrier(0);                                     \
        xk[C] = pack_frag(afb[(C) & 7][0], afb[(C) & 7][1]);                   \
        short8 b0 = *(const short8*)&wt[l15 * WT_STR + (C) * 32 + quad * 8];   \
        short8 b1 = *(const short8*)&wt[(16 + l15) * WT_STR + (C) * 32 + quad * 8]; \
        acc0 = __builtin_amdgcn_mfma_f32_16x16x32_bf16(xk[C], b0, acc0, 0, 0, 0); \
        acc1 = __builtin_amdgcn_mfma_f32_16x16x32_bf16(xk[C], b1, acc1, 0, 0, 0); \
    }

// stage this thread's 4 xk chunks (32 bf16) into xt[d][pos], transposed +
// swizzled. Row r = cc*32+quad*8+j, col = (wv*16+l15) ^ (((cc*4+quad)&7)<<3).
// Quarter-wave: same row, 16 cols in 32B => 8 banks, 2-way (free).
#define P2_STAGE_REG(DC)                                                       \
    _Pragma("unroll")                                                          \
    for (int cc = 0; cc < 4; ++cc) {                                           \
        const int swz = ((cc * 4 + quad) & 7) << 3;                            \
        const int col = (wv * 16 + l15) ^ swz;                                 \
        _Pragma("unroll")                                                      \
        for (int j = 0; j < 8; ++j)                                            \
            xt[(cc * 32 + quad * 8 + j) * XT_STR + col] =                      \
                (unsigned short)xk[(DC) / 32 + cc][j];                         \
    }

#define P2_MFMA_STORE(DC)                                                      \
    {                                                                          \
        f32x4 z = {0.f, 0.f, 0.f, 0.f};                                        \
        f32x4 pacc[2][2];                                                      \
        pacc[0][0] = z; pacc[0][1] = z; pacc[1][0] = z; pacc[1][1] = z;        \
        _Pragma("unroll")                                                      \
        for (int s_ = 0; s_ < 2; ++s_) {                                       \
            const int pb = s_ * 32 + quad * 8;                                 \
            short8 bf0 = *(const short8*)&aT[l15 * AT_STR + pb];               \
            short8 bf1 = *(const short8*)&aT[(16 + l15) * AT_STR + pb];        \
            _Pragma("unroll")                                                  \
            for (int m2 = 0; m2 < 2; ++m2) {                                   \
                const int dloc = wv * 32 + m2 * 16 + l15;                      \
                short8 af = *(const short8*)&xt[dloc * XT_STR + (pb ^ (((dloc >> 3) & 7) << 3))]; \
                pacc[m2][0] = __builtin_amdgcn_mfma_f32_16x16x32_bf16(af, bf0, pacc[m2][0], 0, 0, 0); \
                pacc[m2][1] = __builtin_amdgcn_mfma_f32_16x16x32_bf16(af, bf1, pacc[m2][1], 0, 0, 0); \
            }                                                                  \
        }                                                                      \
        _Pragma("unroll")                                                      \
        for (int m2 = 0; m2 < 2; ++m2) {                                       \
            const int dr = (DC) + (wv * 2 + m2) * 16 + quad * 4;               \
            _Pragma("unroll")                                                  \
            for (int r = 0; r < 4; ++r) {                                      \
                vp[(size_t)(dr + r) * KCL + l15]      = pacc[m2][0][r];        \
                vp[(size_t)(dr + r) * KCL + 16 + l15] = pacc[m2][1][r];        \
            }                                                                  \
        }                                                                      \
    }

__global__ __launch_bounds__(256, 3) void k_sax(const float* __restrict__ x,
                                                const float* __restrict__ Wc,
                                                float* __restrict__ vpart,
                                                float* __restrict__ a_sum) {
    __shared__ __align__(16) unsigned short wt[32 * WT_STR];  // 33280 B (phase-2: xt[128][72] overlay)
    __shared__ __align__(16) unsigned short aT[KCL * AT_STR]; //  4608 B
    __shared__ float asum_l[4][32];                           //   512 B
    const int t    = threadIdx.x;
    const int lane = t & 63;
    const int wv   = t >> 6;
    const int l15  = lane & 15;
    const int quad = lane >> 4;
    const int n0   = blockIdx.x * 64;
    const int b    = n0 / HW;          // uniform per block (64 | 3136)
    const int ch   = blockIdx.x % NCHK;

    // ---- phase-1 A-frag base: this wave's pos row l15, d offset quad*8
    const float* xr = x + (size_t)(n0 + wv * 16 + l15) * DIM + quad * 8;

    // prologue: pin-issue pairs for chunks 0..7 (latency hides under staging)
    f32x4 afb[8][2];
#pragma unroll
    for (int c = 0; c < 8; ++c) {
        afb[c][0] = gload4(xr + c * 32);
        afb[c][1] = gload4(xr + c * 32 + 4);
    }

    // ---- stage WcT[32 k][512 d] bf16, once (compiler loads, L2-hot)
#pragma unroll
    for (int i = 0; i < 16; ++i) {
        int f  = i * 256 + t;          // 0..4095 float4s of Wc
        int d  = f >> 3;               // 0..511
        int k4 = (f & 7) * 4;
        float4 v = *(const float4*)(Wc + (size_t)d * KCL + k4);
        wt[(k4 + 0) * WT_STR + d] = f2bf(v.x);
        wt[(k4 + 1) * WT_STR + d] = f2bf(v.y);
        wt[(k4 + 2) * WT_STR + d] = f2bf(v.z);
        wt[(k4 + 3) * WT_STR + d] = f2bf(v.w);
    }
    HBAR();                            // barrier #1: wt visible; x loads LIVE

    // ---- phase-1: 16 chunks of 32 d, no block barriers; counted vmcnt;
    //      bf16 fragments persist in xk[] for phase-2.
    short8 xk[16];
    f32x4 acc0 = {0.f, 0.f, 0.f, 0.f};
    f32x4 acc1 = {0.f, 0.f, 0.f, 0.f};
    P1_ITER(0)  P1_ITER(1)  P1_ITER(2)  P1_ITER(3)
    P1_ITER(4)  P1_ITER(5)  P1_ITER(6)  P1_ITER(7)
    P1_TAIL(8, 14)  P1_TAIL(9, 12)  P1_TAIL(10, 10) P1_TAIL(11, 8)
    P1_TAIL(12, 6)  P1_TAIL(13, 4)  P1_TAIL(14, 2)  P1_TAIL(15, 0)

    // ---- softmax over 32 k per position (row = quad*4+reg, col k = l15/+16)
    float at0 = 0.f, at1 = 0.f;
#pragma unroll
    for (int r = 0; r < 4; ++r) {
        float m = fmaxf(acc0[r], acc1[r]);
        m = fmaxf(m, __shfl_xor(m, 1));
        m = fmaxf(m, __shfl_xor(m, 2));
        m = fmaxf(m, __shfl_xor(m, 4));
        m = fmaxf(m, __shfl_xor(m, 8));
        float e0 = __expf(acc0[r] - m);
        float e1 = __expf(acc1[r] - m);
        float s = e0 + e1;
        s += __shfl_xor(s, 1);
        s += __shfl_xor(s, 2);
        s += __shfl_xor(s, 4);
        s += __shfl_xor(s, 8);
        float inv = 1.f / s;
        float a0 = e0 * inv, a1 = e1 * inv;
        const int pos = wv * 16 + quad * 4 + r;        // local 0..63
        aT[l15 * AT_STR + pos]        = f2bf(a0);
        aT[(16 + l15) * AT_STR + pos] = f2bf(a1);
        at0 += a0; at1 += a1;
    }
    at0 += __shfl_xor(at0, 16); at0 += __shfl_xor(at0, 32);
    at1 += __shfl_xor(at1, 16); at1 += __shfl_xor(at1, 32);
    if (quad == 0) {
        asum_l[wv][l15]      = at0;
        asum_l[wv][16 + l15] = at1;
    }

    unsigned short* xt = wt;           // overlay (wt dead after barrier #2)
    float* vp = vpart + (size_t)ch * SLABF + (size_t)b * DIM * KCL;

    __syncthreads();                   // barrier #2: aT/asum ready, wt dead

    // ---- phase-2: 4 chunks of 128 d; transpose from REGISTERS (no VMEM
    // loads); 2 lgkm hand-barriers per chunk; vpart stores never drained.
    P2_STAGE_REG(0);
    HBAR();                            // RAW: xt chunk-0 visible
    P2_MFMA_STORE(0);
    HBAR();                            // WAR: chunk-0 reads done
    P2_STAGE_REG(128);
    HBAR();
    P2_MFMA_STORE(128);
    HBAR();
    P2_STAGE_REG(256);
    HBAR();
    P2_MFMA_STORE(256);
    HBAR();
    P2_STAGE_REG(384);
    HBAR();
    P2_MFMA_STORE(384);

    // a_sum atomic at end (outside all counted regions)
    if (t < 32)
        atomAddF(&a_sum[b * KCL + t],
                 asum_l[0][t] + asum_l[1][t] + asum_l[2][t] + asum_l[3][t]);
}

// ---------------- K3: reduce chunk slabs + C*a_sum + intra-normalize -------
// grid 1024, block 256: 8 rows x 32 k; compile-time 49-slab loop, unroll x4.
// 51 MB / ~9us = 5.7 TB/s -- at roofline, unchanged.
__global__ __launch_bounds__(256) void k_norm1(const float* __restrict__ vpart,
                                               const float* __restrict__ a_sum,
                                               const float* __restrict__ Cc,
                                               float* __restrict__ out,
                                               float* __restrict__ ssq) {
    const int t = threadIdx.x;
    const int row = blockIdx.x * 8 + (t >> 5);
    const int k = t & 31;
    const int b = row >> 9;            // uniform per block (8 | 512)
    const int d = row & 511;

    const float* vp = vpart + (size_t)row * KCL + k;
    float s0 = 0.f, s1 = 0.f, s2 = 0.f, s3 = 0.f;
#pragma unroll
    for (int ps = 0; ps < 48; ps += 4) {
        s0 += vp[(size_t)(ps + 0) * SLABF];
        s1 += vp[(size_t)(ps + 1) * SLABF];
        s2 += vp[(size_t)(ps + 2) * SLABF];
        s3 += vp[(size_t)(ps + 3) * SLABF];
    }
    s0 += vp[(size_t)48 * SLABF];
    float v = (s0 + s1) + (s2 + s3) + Cc[d * KCL + k] * a_sum[b * KCL + k];

    float ss = v * v;
    ss += __shfl_xor(ss, 1, 32);  ss += __shfl_xor(ss, 2, 32);
    ss += __shfl_xor(ss, 4, 32);  ss += __shfl_xor(ss, 8, 32);
    ss += __shfl_xor(ss, 16, 32);
    float inv = 1.f / fmaxf(sqrtf(ss), 1e-12f);
    float r = v * inv;
    out[(size_t)row * KCL + k] = r;

    float bs = r * r;
    for (int off = 32; off > 0; off >>= 1) bs += __shfl_down(bs, off, 64);
    __shared__ float red[4];
    if ((t & 63) == 0) red[t >> 6] = bs;
    __syncthreads();
    if (t == 0) atomAddF(&ssq[b], (red[0] + red[1]) + (red[2] + red[3]));
}

// ---------------- K4: final global L2 normalize ----------------
__global__ __launch_bounds__(256) void k_norm2(float* __restrict__ out,
                                               const float* __restrict__ ssq) {
    const int i4 = blockIdx.x * 256 + threadIdx.x;
    const int b = i4 >> 12;
    float inv = 1.f / fmaxf(sqrtf(ssq[b]), 1e-12f);
    float4 v = *(float4*)(out + (size_t)i4 * 4);
    v.x *= inv; v.y *= inv; v.z *= inv; v.w *= inv;
    *(float4*)(out + (size_t)i4 * 4) = v;
}

extern "C" void kernel_launch(void* const* d_in, const int* in_sizes, int n_in,
                              void* d_out, int out_size, void* d_ws, size_t ws_size,
                              hipStream_t stream) {
    const float* x  = (const float*)d_in[0];
    const float* Wc = (const float*)d_in[1];
    const float* Cc = (const float*)d_in[2];
    float* out = (float*)d_out;

    // ws: vpart 49 padded slabs (51.5 MB) | a_sum (2 KB) | ssq (64 B)
    char* ws = (char*)d_ws;
    float* vpart = (float*)ws;
    float* a_sum = (float*)(ws + (size_t)NCHK * SLABF * 4);
    float* ssq   = (float*)(ws + (size_t)NCHK * SLABF * 4 + 2048);

    hipMemsetAsync(a_sum, 0, 2048 + 64, stream);

    k_sax  <<<784, 256, 0, stream>>>(x, Wc, vpart, a_sum);
    k_norm1<<<1024, 256, 0, stream>>>(vpart, a_sum, Cc, out, ssq);
    k_norm2<<<256, 256, 0, stream>>>(out, ssq);
}

// Round 11
// 190.810 us; speedup vs baseline: 1.0386x; 1.0040x over previous
//
#include <hip/hip_runtime.h>
#include <math.h>

// NetVLAD: B=16, H=W=56 (HW=3136), D=512, K=32, fp32 in/out.
// Round 18: REVERT to R14 (best verified: 191.58us, absmax 1.22e-4).
// R16/R17 (chunk-pairing) both failed with bit-identical absmax 2.24e-2
// across different binaries => deterministic logic bug in the paired
// structure, not a spill race; two audits failed to localize it. Per rigor
// rules, bank the known-good kernel rather than iterate blind on an
// unexplained failure.
// R14 structure (verified): keep x in registers between phases.
//  - phase-1 A-frags direct global->reg via pinned asm loads (8-pair
//    pipeline, counted vmcnt), persisted as bf16 xk[16] (64 VGPR).
//  - wt = WcT[32k][512d] bf16 staged once (hand lgkm-only barrier keeps the
//    prologue loads in flight).
//  - softmax fully in-wave -> aT[k][pos] bf16 in LDS.
//  - phase-2: xt[d][pos] (overlay on wt) staged FROM xk regs (cross-wave
//    transpose, XOR-swizzled pos granule 8, 2 lgkm hand-barriers per 128-d
//    chunk); MFMA v[d,k] += x^T.a; per-chunk vpart slab stores never drained
//    by barriers.
// Duration accounting (closed): ~117us harness 392MB poison fills (fixed) +
// k_sax ~66 + k_norm1 ~9 (5.7TB/s roofline) + k_norm2 ~1.

#define BATCH 16
#define HW    3136
#define DIM   512
#define KCL   32
#define NCHK  49                     // 64-pos chunks per batch (49*64 = 3136)
#define SLABF (BATCH * DIM * KCL + 256)   // padded slab stride in floats

typedef __attribute__((ext_vector_type(8))) short short8;
typedef __attribute__((ext_vector_type(4))) float f32x4;

__device__ __forceinline__ void atomAddF(float* p, float v) {
    unsafeAtomicAdd(p, v);
}

__device__ __forceinline__ unsigned short f2bf(float f) {  // RNE fp32->bf16
    unsigned u = __float_as_uint(f);
    return (unsigned short)((u + 0x7FFFu + ((u >> 16) & 1u)) >> 16);
}

__device__ __forceinline__ short8 pack_frag(f32x4 lo, f32x4 hi) {
    union { unsigned short h[8]; short8 s; } r;
    r.h[0] = f2bf(lo[0]); r.h[1] = f2bf(lo[1]); r.h[2] = f2bf(lo[2]); r.h[3] = f2bf(lo[3]);
    r.h[4] = f2bf(hi[0]); r.h[5] = f2bf(hi[1]); r.h[6] = f2bf(hi[2]); r.h[7] = f2bf(hi[3]);
    return r.s;
}

// Pinned-issue loads: volatile asm cannot be sunk; result invalid until
// an explicit counted s_waitcnt vmcnt.
__device__ __forceinline__ f32x4 gload4(const float* p) {
    f32x4 r;
    asm volatile("global_load_dwordx4 %0, %1, off" : "=v"(r) : "v"(p) : "memory");
    return r;
}

#define WAITV(N)                                                               \
    do {                                                                       \
        asm volatile("s_waitcnt vmcnt(" #N ")" ::: "memory");                  \
        __builtin_amdgcn_sched_barrier(0);                                     \
    } while (0)

// lgkm-only barrier: LDS visibility without draining in-flight VMEM
// (prologue loads across barrier #1; vpart stores across phase-2 barriers).
#define HBAR()                                                                 \
    do {                                                                       \
        __builtin_amdgcn_sched_barrier(0);                                     \
        asm volatile("s_waitcnt lgkmcnt(0)\n\ts_barrier" ::: "memory");        \
        __builtin_amdgcn_sched_barrier(0);                                     \
    } while (0)

// ---------------- K1: s = x.Wc (MFMA) + softmax (in LDS) + v = xT.a --------
// grid 784 (16 b x 49 chunks), block 256 = 4 waves, LDS 38400B.
// Phase-1 frags: A[m=l15 (pos)][k=quad*8+j (d)] direct global->reg (asm,
// 8-deep pipeline), persisted as bf16 in xk[16]; B[k][n=l15] from wt
// (WcT[32k][512d] bf16, staged once); D[row=quad*4+reg][col=l15]
// (m89/m120 layouts). Softmax -> aT[k][pos] bf16.
// Phase-2: per 128-d chunk, xt[d][pos] (overlay on wt) staged FROM xk regs
// (cross-wave transpose, 2 lgkm hand-barriers/chunk); pos XOR-swizzled
// granule 8 by row (2-way bank-free writes + reads). MFMA D[m=d][n=k] +=
// A[d][pos].B[pos][k]; store slab.
#define WT_STR 520   // shorts per k row of WcT (512 d + 8 pad)
#define AT_STR 72    // shorts per k row of aT  (64 pos + 8 pad)
#define XT_STR 72    // shorts per d row of xt  (64 pos + 8 pad)

#define P1_ITER(C)                                                             \
    {                                                                          \
        WAITV(14);                                                             \
        xk[C] = pack_frag(afb[(C) & 7][0], afb[(C) & 7][1]);                   \
        afb[(C) & 7][0] = gload4(xr + ((C) + 8) * 32);                         \
        afb[(C) & 7][1] = gload4(xr + ((C) + 8) * 32 + 4);                     \
        short8 b0 = *(const short8*)&wt[l15 * WT_STR + (C) * 32 + quad * 8];   \
        short8 b1 = *(const short8*)&wt[(16 + l15) * WT_STR + (C) * 32 + quad * 8]; \
        acc0 = __builtin_amdgcn_mfma_f32_16x16x32_bf16(xk[C], b0, acc0, 0, 0, 0); \
        acc1 = __builtin_amdgcn_mfma_f32_16x16x32_bf16(xk[C], b1, acc1, 0, 0, 0); \
    }

#define P1_TAIL(C, N)                                                          \
    {                                                                          \
        asm volatile("s_waitcnt vmcnt(" #N ")" ::: "memory");                  \
        __builtin_amdgcn_sched_barrier(0);                                     \
        xk[C] = pack_frag(afb[(C) & 7][0], afb[(C) & 7][1]);                   \
        short8 b0 = *(const short8*)&wt[l15 * WT_STR + (C) * 32 + quad * 8];   \
        short8 b1 = *(const short8*)&wt[(16 + l15) * WT_STR + (C) * 32 + quad * 8]; \
        acc0 = __builtin_amdgcn_mfma_f32_16x16x32_bf16(xk[C], b0, acc0, 0, 0, 0); \
        acc1 = __builtin_amdgcn_mfma_f32_16x16x32_bf16(xk[C], b1, acc1, 0, 0, 0); \
    }

// stage this thread's 4 xk chunks (32 bf16) into xt[d][pos], transposed +
// swizzled. Row r = cc*32+quad*8+j, col = (wv*16+l15) ^ (((cc*4+quad)&7)<<3).
// Quarter-wave: same row, 16 cols in 32B => 8 banks, 2-way (free).
#define P2_STAGE_REG(DC)                                                       \
    _Pragma("unroll")                                                          \
    for (int cc = 0; cc < 4; ++cc) {                                           \
        const int swz = ((cc * 4 + quad) & 7) << 3;                            \
        const int col = (wv * 16 + l15) ^ swz;                                 \
        _Pragma("unroll")                                                      \
        for (int j = 0; j < 8; ++j)                                            \
            xt[(cc * 32 + quad * 8 + j) * XT_STR + col] =                      \
                (unsigned short)xk[(DC) / 32 + cc][j];                         \
    }

#define P2_MFMA_STORE(DC)                                                      \
    {                                                                          \
        f32x4 z = {0.f, 0.f, 0.f, 0.f};                                        \
        f32x4 pacc[2][2];                                                      \
        pacc[0][0] = z; pacc[0][1] = z; pacc[1][0] = z; pacc[1][1] = z;        \
        _Pragma("unroll")                                                      \
        for (int s_ = 0; s_ < 2; ++s_) {                                       \
            const int pb = s_ * 32 + quad * 8;                                 \
            short8 bf0 = *(const short8*)&aT[l15 * AT_STR + pb];               \
            short8 bf1 = *(const short8*)&aT[(16 + l15) * AT_STR + pb];        \
            _Pragma("unroll")                                                  \
            for (int m2 = 0; m2 < 2; ++m2) {                                   \
                const int dloc = wv * 32 + m2 * 16 + l15;                      \
                short8 af = *(const short8*)&xt[dloc * XT_STR + (pb ^ (((dloc >> 3) & 7) << 3))]; \
                pacc[m2][0] = __builtin_amdgcn_mfma_f32_16x16x32_bf16(af, bf0, pacc[m2][0], 0, 0, 0); \
                pacc[m2][1] = __builtin_amdgcn_mfma_f32_16x16x32_bf16(af, bf1, pacc[m2][1], 0, 0, 0); \
            }                                                                  \
        }                                                                      \
        _Pragma("unroll")                                                      \
        for (int m2 = 0; m2 < 2; ++m2) {                                       \
            const int dr = (DC) + (wv * 2 + m2) * 16 + quad * 4;               \
            _Pragma("unroll")                                                  \
            for (int r = 0; r < 4; ++r) {                                      \
                vp[(size_t)(dr + r) * KCL + l15]      = pacc[m2][0][r];        \
                vp[(size_t)(dr + r) * KCL + 16 + l15] = pacc[m2][1][r];        \
            }                                                                  \
        }                                                                      \
    }

__global__ __launch_bounds__(256, 3) void k_sax(const float* __restrict__ x,
                                                const float* __restrict__ Wc,
                                                float* __restrict__ vpart,
                                                float* __restrict__ a_sum) {
    __shared__ __align__(16) unsigned short wt[32 * WT_STR];  // 33280 B (phase-2: xt[128][72] overlay)
    __shared__ __align__(16) unsigned short aT[KCL * AT_STR]; //  4608 B
    __shared__ float asum_l[4][32];                           //   512 B
    const int t    = threadIdx.x;
    const int lane = t & 63;
    const int wv   = t >> 6;
    const int l15  = lane & 15;
    const int quad = lane >> 4;
    const int n0   = blockIdx.x * 64;
    const int b    = n0 / HW;          // uniform per block (64 | 3136)
    const int ch   = blockIdx.x % NCHK;

    // ---- phase-1 A-frag base: this wave's pos row l15, d offset quad*8
    const float* xr = x + (size_t)(n0 + wv * 16 + l15) * DIM + quad * 8;

    // prologue: pin-issue pairs for chunks 0..7 (latency hides under staging)
    f32x4 afb[8][2];
#pragma unroll
    for (int c = 0; c < 8; ++c) {
        afb[c][0] = gload4(xr + c * 32);
        afb[c][1] = gload4(xr + c * 32 + 4);
    }

    // ---- stage WcT[32 k][512 d] bf16, once (compiler loads, L2-hot)
#pragma unroll
    for (int i = 0; i < 16; ++i) {
        int f  = i * 256 + t;          // 0..4095 float4s of Wc
        int d  = f >> 3;               // 0..511
        int k4 = (f & 7) * 4;
        float4 v = *(const float4*)(Wc + (size_t)d * KCL + k4);
        wt[(k4 + 0) * WT_STR + d] = f2bf(v.x);
        wt[(k4 + 1) * WT_STR + d] = f2bf(v.y);
        wt[(k4 + 2) * WT_STR + d] = f2bf(v.z);
        wt[(k4 + 3) * WT_STR + d] = f2bf(v.w);
    }
    HBAR();                            // barrier #1: wt visible; x loads LIVE

    // ---- phase-1: 16 chunks of 32 d, no block barriers; counted vmcnt;
    //      bf16 fragments persist in xk[] for phase-2.
    short8 xk[16];
    f32x4 acc0 = {0.f, 0.f, 0.f, 0.f};
    f32x4 acc1 = {0.f, 0.f, 0.f, 0.f};
    P1_ITER(0)  P1_ITER(1)  P1_ITER(2)  P1_ITER(3)
    P1_ITER(4)  P1_ITER(5)  P1_ITER(6)  P1_ITER(7)
    P1_TAIL(8, 14)  P1_TAIL(9, 12)  P1_TAIL(10, 10) P1_TAIL(11, 8)
    P1_TAIL(12, 6)  P1_TAIL(13, 4)  P1_TAIL(14, 2)  P1_TAIL(15, 0)

    // ---- softmax over 32 k per position (row = quad*4+reg, col k = l15/+16)
    float at0 = 0.f, at1 = 0.f;
#pragma unroll
    for (int r = 0; r < 4; ++r) {
        float m = fmaxf(acc0[r], acc1[r]);
        m = fmaxf(m, __shfl_xor(m, 1));
        m = fmaxf(m, __shfl_xor(m, 2));
        m = fmaxf(m, __shfl_xor(m, 4));
        m = fmaxf(m, __shfl_xor(m, 8));
        float e0 = __expf(acc0[r] - m);
        float e1 = __expf(acc1[r] - m);
        float s = e0 + e1;
        s += __shfl_xor(s, 1);
        s += __shfl_xor(s, 2);
        s += __shfl_xor(s, 4);
        s += __shfl_xor(s, 8);
        float inv = 1.f / s;
        float a0 = e0 * inv, a1 = e1 * inv;
        const int pos = wv * 16 + quad * 4 + r;        // local 0..63
        aT[l15 * AT_STR + pos]        = f2bf(a0);
        aT[(16 + l15) * AT_STR + pos] = f2bf(a1);
        at0 += a0; at1 += a1;
    }
    at0 += __shfl_xor(at0, 16); at0 += __shfl_xor(at0, 32);
    at1 += __shfl_xor(at1, 16); at1 += __shfl_xor(at1, 32);
    if (quad == 0) {
        asum_l[wv][l15]      = at0;
        asum_l[wv][16 + l15] = at1;
    }

    unsigned short* xt = wt;           // overlay (wt dead after barrier #2)
    float* vp = vpart + (size_t)ch * SLABF + (size_t)b * DIM * KCL;

    __syncthreads();                   // barrier #2: aT/asum ready, wt dead

    // ---- phase-2: 4 chunks of 128 d; transpose from REGISTERS (no VMEM
    // loads); 2 lgkm hand-barriers per chunk; vpart stores never drained.
    P2_STAGE_REG(0);
    HBAR();                            // RAW: xt chunk-0 visible
    P2_MFMA_STORE(0);
    HBAR();                            // WAR: chunk-0 reads done
    P2_STAGE_REG(128);
    HBAR();
    P2_MFMA_STORE(128);
    HBAR();
    P2_STAGE_REG(256);
    HBAR();
    P2_MFMA_STORE(256);
    HBAR();
    P2_STAGE_REG(384);
    HBAR();
    P2_MFMA_STORE(384);

    // a_sum atomic at end (outside all counted regions)
    if (t < 32)
        atomAddF(&a_sum[b * KCL + t],
                 asum_l[0][t] + asum_l[1][t] + asum_l[2][t] + asum_l[3][t]);
}

// ---------------- K3: reduce chunk slabs + C*a_sum + intra-normalize -------
// grid 1024, block 256: 8 rows x 32 k; compile-time 49-slab loop, unroll x4.
// 51 MB / ~9us = 5.7 TB/s -- at roofline, unchanged.
__global__ __launch_bounds__(256) void k_norm1(const float* __restrict__ vpart,
                                               const float* __restrict__ a_sum,
                                               const float* __restrict__ Cc,
                                               float* __restrict__ out,
                                               float* __restrict__ ssq) {
    const int t = threadIdx.x;
    const int row = blockIdx.x * 8 + (t >> 5);
    const int k = t & 31;
    const int b = row >> 9;            // uniform per block (8 | 512)
    const int d = row & 511;

    const float* vp = vpart + (size_t)row * KCL + k;
    float s0 = 0.f, s1 = 0.f, s2 = 0.f, s3 = 0.f;
#pragma unroll
    for (int ps = 0; ps < 48; ps += 4) {
        s0 += vp[(size_t)(ps + 0) * SLABF];
        s1 += vp[(size_t)(ps + 1) * SLABF];
        s2 += vp[(size_t)(ps + 2) * SLABF];
        s3 += vp[(size_t)(ps + 3) * SLABF];
    }
    s0 += vp[(size_t)48 * SLABF];
    float v = (s0 + s1) + (s2 + s3) + Cc[d * KCL + k] * a_sum[b * KCL + k];

    float ss = v * v;
    ss += __shfl_xor(ss, 1, 32);  ss += __shfl_xor(ss, 2, 32);
    ss += __shfl_xor(ss, 4, 32);  ss += __shfl_xor(ss, 8, 32);
    ss += __shfl_xor(ss, 16, 32);
    float inv = 1.f / fmaxf(sqrtf(ss), 1e-12f);
    float r = v * inv;
    out[(size_t)row * KCL + k] = r;

    float bs = r * r;
    for (int off = 32; off > 0; off >>= 1) bs += __shfl_down(bs, off, 64);
    __shared__ float red[4];
    if ((t & 63) == 0) red[t >> 6] = bs;
    __syncthreads();
    if (t == 0) atomAddF(&ssq[b], (red[0] + red[1]) + (red[2] + red[3]));
}

// ---------------- K4: final global L2 normalize ----------------
__global__ __launch_bounds__(256) void k_norm2(float* __restrict__ out,
                                               const float* __restrict__ ssq) {
    const int i4 = blockIdx.x * 256 + threadIdx.x;
    const int b = i4 >> 12;
    float inv = 1.f / fmaxf(sqrtf(ssq[b]), 1e-12f);
    float4 v = *(float4*)(out + (size_t)i4 * 4);
    v.x *= inv; v.y *= inv; v.z *= inv; v.w *= inv;
    *(float4*)(out + (size_t)i4 * 4) = v;
}

extern "C" void kernel_launch(void* const* d_in, const int* in_sizes, int n_in,
                              void* d_out, int out_size, void* d_ws, size_t ws_size,
                              hipStream_t stream) {
    const float* x  = (const float*)d_in[0];
    const float* Wc = (const float*)d_in[1];
    const float* Cc = (const float*)d_in[2];
    float* out = (float*)d_out;

    // ws: vpart 49 padded slabs (51.5 MB) | a_sum (2 KB) | ssq (64 B)
    char* ws = (char*)d_ws;
    float* vpart = (float*)ws;
    float* a_sum = (float*)(ws + (size_t)NCHK * SLABF * 4);
    float* ssq   = (float*)(ws + (size_t)NCHK * SLABF * 4 + 2048);

    hipMemsetAsync(a_sum, 0, 2048 + 64, stream);

    k_sax  <<<784, 256, 0, stream>>>(x, Wc, vpart, a_sum);
    k_norm1<<<1024, 256, 0, stream>>>(vpart, a_sum, Cc, out, ssq);
    k_norm2<<<256, 256, 0, stream>>>(out, ssq);
}